// Round 1
// baseline (418.628 us; speedup 1.0000x reference)
//
#include <hip/hip_runtime.h>

// MSTGCN head, fully fused fp32 implementation.
// Key simplification: adjacency = I  =>  cheb = [I, -I, I]  =>  the Chebyshev
// graph conv is a plain per-(b,n) GEMM with te = theta[0]-theta[1]+theta[2].
//
// Shapes: B=32, N=512, T=12, F_IN=128, K=3, CF=64, TF=64, PRED=12.
// 16384 independent (b,n) pairs. One wave handles 2 pairs end-to-end.

#define NT 12

// ws float offsets (prepped / transposed weights)
#define OFF_TE0   0        // 128*64: te0[f*64+o]
#define OFF_TE1   8192     // 64*64
#define OFF_RWT0  12288    // 128*64: rw0 transposed [f*64+o]
#define OFF_RWT1  20480    // 64*64
#define OFF_TWT0  24576    // 192*64: tw0 transposed [(c*3+dt)*64+o]
#define OFF_TWT1  36864    // 192*64
// total 49152 floats = 192 KB of ws

__global__ void prep_kernel(const float* __restrict__ th0, const float* __restrict__ th1,
                            const float* __restrict__ tw0, const float* __restrict__ tw1,
                            const float* __restrict__ rw0, const float* __restrict__ rw1,
                            float* __restrict__ ws)
{
    int i = blockIdx.x * 256 + threadIdx.x;   // 0..12287
    if (i < 8192)  ws[OFF_TE0 + i] = th0[i] - th0[8192 + i] + th0[16384 + i];
    if (i < 4096)  ws[OFF_TE1 + i] = th1[i] - th1[4096 + i] + th1[8192 + i];
    if (i < 8192)  { int f = i >> 6, o = i & 63; ws[OFF_RWT0 + i] = rw0[o * 128 + f]; }
    if (i < 4096)  { int f = i >> 6, o = i & 63; ws[OFF_RWT1 + i] = rw1[o * 64 + f]; }
    if (i < 12288) { int cd = i >> 6, o = i & 63;
                     ws[OFF_TWT0 + i] = tw0[o * 192 + cd];
                     ws[OFF_TWT1 + i] = tw1[o * 192 + cd]; }
}

// Per pair, LDS row of 1536 floats (aliased across phases):
//   [0..1535]  : X (12 x 128)             (phase A/B block 0 input)
//   [768..1535]: s-tile (12 x 64)         (written after A/B, read by tconv)
//   [0..767]   : block0 LN output = block1 input (12 x 64)
__global__ __launch_bounds__(256) void mstgcn_fused(
    const float* __restrict__ x,   const float* __restrict__ ws,
    const float* __restrict__ tb0, const float* __restrict__ rb0,
    const float* __restrict__ lg0, const float* __restrict__ lb0,
    const float* __restrict__ tb1, const float* __restrict__ rb1,
    const float* __restrict__ lg1, const float* __restrict__ lb1,
    const float* __restrict__ fw,  const float* __restrict__ fb,
    float* __restrict__ out)
{
    __shared__ __align__(16) float BUF[8][1536];   // 48 KB

    const int lane  = threadIdx.x & 63;
    const int wave  = threadIdx.x >> 6;
    const int pair0 = blockIdx.x * 8 + wave * 2;   // this wave: pair0, pair0+1

    float* B0 = &BUF[wave * 2 + 0][0];
    float* B1 = &BUF[wave * 2 + 1][0];

    // ---- stage X (2 pairs x 12 x 128 floats) into LDS ----
    {
        const float4* s0 = (const float4*)(x + (size_t)pair0 * 1536);
        const float4* s1 = (const float4*)(x + (size_t)(pair0 + 1) * 1536);
        float4* d0 = (float4*)B0;
        float4* d1 = (float4*)B1;
        #pragma unroll
        for (int i = 0; i < 6; ++i) {
            d0[lane + 64 * i] = s0[lane + 64 * i];
            d1[lane + 64 * i] = s1[lane + 64 * i];
        }
    }
    __syncthreads();

    float h[2][NT];   // r-conv + t-conv accumulation (pre-relu, pre-LN)

    // ================= BLOCK 0: cheb GEMM (s) + residual 1x1 (r) =================
    {
        float as[2][NT], ar[2][NT];
        #pragma unroll
        for (int p = 0; p < 2; ++p)
            #pragma unroll
            for (int t = 0; t < NT; ++t) { as[p][t] = 0.f; ar[p][t] = 0.f; }

        const float* te  = ws + OFF_TE0;
        const float* rwT = ws + OFF_RWT0;
        #pragma unroll 4
        for (int f = 0; f < 128; ++f) {
            float w1 = te[f * 64 + lane];
            float w2 = rwT[f * 64 + lane];
            #pragma unroll
            for (int t = 0; t < NT; ++t) {
                float x0 = B0[t * 128 + f];
                float x1 = B1[t * 128 + f];
                as[0][t] = fmaf(x0, w1, as[0][t]);
                ar[0][t] = fmaf(x0, w2, ar[0][t]);
                as[1][t] = fmaf(x1, w1, as[1][t]);
                ar[1][t] = fmaf(x1, w2, ar[1][t]);
            }
        }
        float rb = rb0[lane], tb = tb0[lane];
        #pragma unroll
        for (int t = 0; t < NT; ++t) {
            B0[768 + t * 64 + lane] = fmaxf(as[0][t], 0.f);   // s = relu(X @ te)
            B1[768 + t * 64 + lane] = fmaxf(as[1][t], 0.f);
            h[0][t] = ar[0][t] + rb + tb;
            h[1][t] = ar[1][t] + rb + tb;
        }
    }
    __syncthreads();

    // ---- temporal conv (1x3, pad 1) block 0 ----
    {
        const float* twT = ws + OFF_TWT0;
        for (int c = 0; c < 64; ++c) {
            float sv0[NT], sv1[NT];
            #pragma unroll
            for (int t = 0; t < NT; ++t) {
                sv0[t] = B0[768 + t * 64 + c];
                sv1[t] = B1[768 + t * 64 + c];
            }
            #pragma unroll
            for (int dt = 0; dt < 3; ++dt) {
                float w = twT[(c * 3 + dt) * 64 + lane];
                #pragma unroll
                for (int t = 0; t < NT; ++t) {
                    int ts = t + dt - 1;
                    if (ts >= 0 && ts < NT) {
                        h[0][t] = fmaf(sv0[ts], w, h[0][t]);
                        h[1][t] = fmaf(sv1[ts], w, h[1][t]);
                    }
                }
            }
        }
    }
    __syncthreads();

    // ---- relu + LayerNorm(64) block 0 -> write block1 input into BUF[0..767] ----
    {
        float lg = lg0[lane], lb = lb0[lane];
        #pragma unroll
        for (int p = 0; p < 2; ++p) {
            float* Bp = p ? B1 : B0;
            #pragma unroll
            for (int t = 0; t < NT; ++t) {
                float v = fmaxf(h[p][t], 0.f);
                float sm = v, sq = v * v;
                #pragma unroll
                for (int off = 32; off > 0; off >>= 1) {
                    sm += __shfl_xor(sm, off, 64);
                    sq += __shfl_xor(sq, off, 64);
                }
                float mu  = sm * 0.015625f;
                float var = sq * 0.015625f - mu * mu;
                float o   = (v - mu) * rsqrtf(var + 1e-5f) * lg + lb;
                Bp[t * 64 + lane] = o;
            }
        }
    }
    __syncthreads();

    // ================= BLOCK 1 (F_in = 64) =================
    {
        float as[2][NT], ar[2][NT];
        #pragma unroll
        for (int p = 0; p < 2; ++p)
            #pragma unroll
            for (int t = 0; t < NT; ++t) { as[p][t] = 0.f; ar[p][t] = 0.f; }

        const float* te  = ws + OFF_TE1;
        const float* rwT = ws + OFF_RWT1;
        #pragma unroll 4
        for (int f = 0; f < 64; ++f) {
            float w1 = te[f * 64 + lane];
            float w2 = rwT[f * 64 + lane];
            #pragma unroll
            for (int t = 0; t < NT; ++t) {
                float x0 = B0[t * 64 + f];
                float x1 = B1[t * 64 + f];
                as[0][t] = fmaf(x0, w1, as[0][t]);
                ar[0][t] = fmaf(x0, w2, ar[0][t]);
                as[1][t] = fmaf(x1, w1, as[1][t]);
                ar[1][t] = fmaf(x1, w2, ar[1][t]);
            }
        }
        float rb = rb1[lane], tb = tb1[lane];
        #pragma unroll
        for (int t = 0; t < NT; ++t) {
            B0[768 + t * 64 + lane] = fmaxf(as[0][t], 0.f);
            B1[768 + t * 64 + lane] = fmaxf(as[1][t], 0.f);
            h[0][t] = ar[0][t] + rb + tb;
            h[1][t] = ar[1][t] + rb + tb;
        }
    }
    __syncthreads();

    // ---- temporal conv block 1 ----
    {
        const float* twT = ws + OFF_TWT1;
        for (int c = 0; c < 64; ++c) {
            float sv0[NT], sv1[NT];
            #pragma unroll
            for (int t = 0; t < NT; ++t) {
                sv0[t] = B0[768 + t * 64 + c];
                sv1[t] = B1[768 + t * 64 + c];
            }
            #pragma unroll
            for (int dt = 0; dt < 3; ++dt) {
                float w = twT[(c * 3 + dt) * 64 + lane];
                #pragma unroll
                for (int t = 0; t < NT; ++t) {
                    int ts = t + dt - 1;
                    if (ts >= 0 && ts < NT) {
                        h[0][t] = fmaf(sv0[ts], w, h[0][t]);
                        h[1][t] = fmaf(sv1[ts], w, h[1][t]);
                    }
                }
            }
        }
    }

    // ---- relu + LN block 1 -> keep in registers ----
    float hn[2][NT];
    {
        float lg = lg1[lane], lb = lb1[lane];
        #pragma unroll
        for (int p = 0; p < 2; ++p) {
            #pragma unroll
            for (int t = 0; t < NT; ++t) {
                float v = fmaxf(h[p][t], 0.f);
                float sm = v, sq = v * v;
                #pragma unroll
                for (int off = 32; off > 0; off >>= 1) {
                    sm += __shfl_xor(sm, off, 64);
                    sq += __shfl_xor(sq, off, 64);
                }
                float mu  = sm * 0.015625f;
                float var = sq * 0.015625f - mu * mu;
                hn[p][t]  = (v - mu) * rsqrtf(var + 1e-5f) * lg + lb;
            }
        }
    }

    // ---- final conv: out[pair][po] = fb[po] + sum_{t,f} hn[t][f]*fw[po][t][f] ----
    {
        #pragma unroll
        for (int po = 0; po < 12; ++po) {
            float a0 = 0.f, a1 = 0.f;
            #pragma unroll
            for (int t = 0; t < NT; ++t) {
                float w = fw[po * 768 + t * 64 + lane];
                a0 = fmaf(hn[0][t], w, a0);
                a1 = fmaf(hn[1][t], w, a1);
            }
            #pragma unroll
            for (int off = 32; off > 0; off >>= 1) {
                a0 += __shfl_xor(a0, off, 64);
                a1 += __shfl_xor(a1, off, 64);
            }
            if (lane == po) {
                float b = fb[po];
                out[(size_t)pair0 * 12 + po]       = a0 + b;
                out[(size_t)(pair0 + 1) * 12 + po] = a1 + b;
            }
        }
    }
}

extern "C" void kernel_launch(void* const* d_in, const int* in_sizes, int n_in,
                              void* d_out, int out_size, void* d_ws, size_t ws_size,
                              hipStream_t stream)
{
    (void)in_sizes; (void)n_in; (void)out_size; (void)ws_size;
    const float* x   = (const float*)d_in[0];
    const float* th0 = (const float*)d_in[1];
    const float* tw0 = (const float*)d_in[2];
    const float* tb0 = (const float*)d_in[3];
    const float* rw0 = (const float*)d_in[4];
    const float* rb0 = (const float*)d_in[5];
    const float* lg0 = (const float*)d_in[6];
    const float* lb0 = (const float*)d_in[7];
    const float* th1 = (const float*)d_in[8];
    const float* tw1 = (const float*)d_in[9];
    const float* tb1 = (const float*)d_in[10];
    const float* rw1 = (const float*)d_in[11];
    const float* rb1 = (const float*)d_in[12];
    const float* lg1 = (const float*)d_in[13];
    const float* lb1 = (const float*)d_in[14];
    const float* fw  = (const float*)d_in[15];
    const float* fb  = (const float*)d_in[16];
    float* out = (float*)d_out;
    float* ws  = (float*)d_ws;

    prep_kernel<<<48, 256, 0, stream>>>(th0, th1, tw0, tw1, rw0, rw1, ws);
    mstgcn_fused<<<2048, 256, 0, stream>>>(x, ws, tb0, rb0, lg0, lb0,
                                           tb1, rb1, lg1, lb1, fw, fb, out);
}

// Round 2
// 104.148 us; speedup vs baseline: 4.0195x; 4.0195x over previous
//
#include <hip/hip_runtime.h>

// MSTGCN head — fused bf16-MFMA implementation.
// cheb = [I,-I,I] (identity adjacency) => graph conv = per-(b,n) GEMM with
// te = theta0 - theta1 + theta2.
//
// Decomposition: 16384 (b,n) pairs. Wave = 4 pairs = 48 rows = 3 M-tiles of 16
// (zero M-padding waste). Block = 4 waves = 16 pairs. Grid = 1024.
// All contractions via v_mfma_f32_16x16x32_bf16:
//   GEMM1 : X(48x128)      @ [te0|rw0T](128x128) -> s | r      (96 MFMA)
//   tconv0: 3 shifted s(48x64) @ TW0_dt(64x64)  += r           (72 MFMA)
//   GEMM2 : y1(48x64)      @ [te1|rw1T](64x128)                (48 MFMA)
//   tconv1: like tconv0                                        (72 MFMA)
//   final : y2(16x768)     @ FW(768x16)  (ks split 6/wave)     ( 6 MFMA)
//
// Fragment maps (gfx950 16x16x32 bf16):
//   A: lane l, elem j -> A[l&15][(l>>4)*8+j]
//   B: lane l, elem j -> B[(l>>4)*8+j][l&15]
//   C/D: lane l, reg j -> D[(l>>4)*4+j][l&15]   (m89-verified)
//
// Weights pre-packed by prep kernel into ws as B-fragment-linear bf16
// (frag = 512 bf16 = 1KB; lane's 8 elems contiguous -> one 16B load).

typedef __attribute__((ext_vector_type(8))) short bf16x8;
typedef __attribute__((ext_vector_type(4))) float f32x4;

#define FR_W1   0     // 32 frags: ks(4)*8 + nt(8)   K=128,N=128 [te0|rw0T]
#define FR_TW0  32    // 24 frags: dt*8 + ks(2)*4 + nt(4)
#define FR_W2   56    // 16 frags: ks(2)*8 + nt(8)   K=64,N=128 [te1|rw1T]
#define FR_TW1  72    // 24 frags
#define FR_FW   96    // 24 frags: ks(24), N=16 (cols 12..15 zero)
#define N_FRAGS 120

__device__ __forceinline__ unsigned short f2bf(float f) {
    unsigned u = __builtin_bit_cast(unsigned, f);
    return (unsigned short)((u + 0x7FFFu + ((u >> 16) & 1u)) >> 16);
}

__global__ void prep(const float* __restrict__ th0, const float* __restrict__ tw0,
                     const float* __restrict__ rw0, const float* __restrict__ th1,
                     const float* __restrict__ tw1, const float* __restrict__ rw1,
                     const float* __restrict__ fw,  short* __restrict__ wsb)
{
    int e = blockIdx.x * 256 + threadIdx.x;     // (frag, lane, i)
    if (e >= N_FRAGS * 512) return;
    int frag = e >> 9;
    int l    = (e >> 3) & 63;
    int i    = e & 7;
    int kif  = ((l >> 4) << 3) + i;             // k within 32-chunk
    int nif  = l & 15;
    float val = 0.f;
    if (frag < 32) {                                       // W1
        int ks = frag >> 3, nt = frag & 7;
        int k = ks * 32 + kif, n = nt * 16 + nif;
        if (n < 64) val = th0[k*64+n] - th0[8192 + k*64+n] + th0[16384 + k*64+n];
        else        val = rw0[(n - 64) * 128 + k];
    } else if (frag < 56) {                                // TW0
        int q = frag - 32; int dt = q >> 3, ks = (q >> 2) & 1, nt = q & 3;
        int c = ks * 32 + kif, o = nt * 16 + nif;
        val = tw0[o * 192 + c * 3 + dt];
    } else if (frag < 72) {                                // W2
        int q = frag - 56; int ks = q >> 3, nt = q & 7;
        int k = ks * 32 + kif, n = nt * 16 + nif;
        if (n < 64) val = th1[k*64+n] - th1[4096 + k*64+n] + th1[8192 + k*64+n];
        else        val = rw1[(n - 64) * 64 + k];
    } else if (frag < 96) {                                // TW1
        int q = frag - 72; int dt = q >> 3, ks = (q >> 2) & 1, nt = q & 3;
        int c = ks * 32 + kif, o = nt * 16 + nif;
        val = tw1[o * 192 + c * 3 + dt];
    } else {                                               // FW
        int ks = frag - 96; int k = ks * 32 + kif; int po = nif;
        val = (po < 12) ? fw[po * 768 + k] : 0.f;
    }
    wsb[e] = (short)f2bf(val);
}

// LDS: per-wave 48x64 bf16 s/y tile (6 KB, XOR-swizzled), block-shared
// final buffer 16x768 bf16 (24 KB, swizzled) + 4x16x16 f32 partials (4 KB).
#define LDS_SY(w)  (LDS + (w) * 6144)
#define LDS_FB     (LDS + 24576)
#define LDS_PB     ((float*)(LDS + 49152))

__global__ __launch_bounds__(256, 3) void mstgcn_mfma(
    const float* __restrict__ x,   const short* __restrict__ wsb,
    const float* __restrict__ tb0, const float* __restrict__ rb0,
    const float* __restrict__ lg0, const float* __restrict__ lb0,
    const float* __restrict__ tb1, const float* __restrict__ rb1,
    const float* __restrict__ lg1, const float* __restrict__ lb1,
    const float* __restrict__ fb,  float* __restrict__ out)
{
    __shared__ __align__(16) char LDS[53248];

    const int lane = threadIdx.x & 63;
    const int wave = threadIdx.x >> 6;
    const int l15  = lane & 15;
    const int l4   = lane >> 4;
    const int pair0 = blockIdx.x * 16 + wave * 4;

    char* syB = LDS_SY(wave);

    auto ldfrag = [&](int f) -> bf16x8 {
        return *(const bf16x8*)(wsb + f * 512 + lane * 8);
    };

    // A-row decode (rows 0..47 within wave; row -> (pair, t))
    int rowA[3], tA[3];
    long gbase[3];
    #pragma unroll
    for (int mt = 0; mt < 3; ++mt) {
        int r = mt * 16 + l15;
        int p = r / 12;
        rowA[mt] = r;
        tA[mt]   = r - p * 12;
        gbase[mt] = ((long)(pair0 + p) * 12 + tA[mt]) * 128;
    }

    // ============ GEMM1: X @ [te0 | rw0T] ============
    f32x4 accS[3][4] = {}, accR[3][4] = {};
    #pragma unroll
    for (int ks = 0; ks < 4; ++ks) {
        bf16x8 a[3];
        #pragma unroll
        for (int mt = 0; mt < 3; ++mt) {
            const float* p = x + gbase[mt] + ks * 32 + l4 * 8;
            float v[8];
            *(float4*)(v)     = *(const float4*)(p);
            *(float4*)(v + 4) = *(const float4*)(p + 4);
            bf16x8 af;
            #pragma unroll
            for (int j = 0; j < 8; ++j) af[j] = (short)f2bf(v[j]);
            a[mt] = af;
        }
        #pragma unroll
        for (int nt = 0; nt < 8; ++nt) {
            bf16x8 b = ldfrag(FR_W1 + ks * 8 + nt);
            #pragma unroll
            for (int mt = 0; mt < 3; ++mt) {
                f32x4& acc = (nt < 4) ? accS[mt][nt] : accR[mt][nt - 4];
                acc = __builtin_amdgcn_mfma_f32_16x16x32_bf16(a[mt], b, acc, 0, 0, 0);
            }
        }
    }
    // epilogue: s = relu(accS) -> LDS (swizzled bf16)
    #pragma unroll
    for (int mt = 0; mt < 3; ++mt)
        #pragma unroll
        for (int j = 0; j < 4; ++j) {
            int row = mt * 16 + l4 * 4 + j;
            int sw  = (row & 7) << 4;
            #pragma unroll
            for (int nt = 0; nt < 4; ++nt) {
                int col = nt * 16 + l15;
                *(short*)(syB + row * 128 + ((col * 2) ^ sw)) =
                    (short)f2bf(fmaxf(accS[mt][nt][j], 0.f));
            }
        }
    __syncthreads();

    // ============ tconv0 (3 shifted GEMMs), C-init = accR ============
    #pragma unroll
    for (int dt = 0; dt < 3; ++dt) {
        #pragma unroll
        for (int ks = 0; ks < 2; ++ks) {
            bf16x8 a[3];
            #pragma unroll
            for (int mt = 0; mt < 3; ++mt) {
                int ts    = tA[mt] + dt - 1;
                bool ok   = (ts >= 0) && (ts < 12);
                int srow  = ok ? (rowA[mt] + dt - 1) : rowA[mt];
                int kb    = (ks * 32 + l4 * 8) * 2;
                bf16x8 av = *(const bf16x8*)(syB + srow * 128 + (kb ^ ((srow & 7) << 4)));
                a[mt] = ok ? av : (bf16x8)(short)0;
            }
            #pragma unroll
            for (int nt = 0; nt < 4; ++nt) {
                bf16x8 b = ldfrag(FR_TW0 + dt * 8 + ks * 4 + nt);
                #pragma unroll
                for (int mt = 0; mt < 3; ++mt)
                    accR[mt][nt] = __builtin_amdgcn_mfma_f32_16x16x32_bf16(a[mt], b, accR[mt][nt], 0, 0, 0);
            }
        }
    }
    __syncthreads();

    // ============ bias + relu + LN0 -> y1 into LDS ============
    {
        float bv[4], lgv[4], lbv[4];
        #pragma unroll
        for (int nt = 0; nt < 4; ++nt) {
            int col = nt * 16 + l15;
            bv[nt]  = rb0[col] + tb0[col];
            lgv[nt] = lg0[col];
            lbv[nt] = lb0[col];
        }
        #pragma unroll
        for (int mt = 0; mt < 3; ++mt)
            #pragma unroll
            for (int j = 0; j < 4; ++j) {
                float v[4], sm = 0.f, sq = 0.f;
                #pragma unroll
                for (int nt = 0; nt < 4; ++nt) {
                    v[nt] = fmaxf(accR[mt][nt][j] + bv[nt], 0.f);
                    sm += v[nt]; sq += v[nt] * v[nt];
                }
                #pragma unroll
                for (int m = 8; m; m >>= 1) {
                    sm += __shfl_xor(sm, m, 64);
                    sq += __shfl_xor(sq, m, 64);
                }
                float mu = sm * 0.015625f;
                float is = rsqrtf(sq * 0.015625f - mu * mu + 1e-5f);
                int row = mt * 16 + l4 * 4 + j;
                int sw  = (row & 7) << 4;
                #pragma unroll
                for (int nt = 0; nt < 4; ++nt) {
                    int col = nt * 16 + l15;
                    *(short*)(syB + row * 128 + ((col * 2) ^ sw)) =
                        (short)f2bf((v[nt] - mu) * is * lgv[nt] + lbv[nt]);
                }
            }
    }
    __syncthreads();

    // ============ GEMM2: y1 @ [te1 | rw1T]  (K=64) ============
    #pragma unroll
    for (int mt = 0; mt < 3; ++mt)
        #pragma unroll
        for (int nt = 0; nt < 4; ++nt) { accS[mt][nt] = (f32x4)0.f; accR[mt][nt] = (f32x4)0.f; }
    #pragma unroll
    for (int ks = 0; ks < 2; ++ks) {
        bf16x8 a[3];
        #pragma unroll
        for (int mt = 0; mt < 3; ++mt) {
            int row = rowA[mt];
            int kb  = (ks * 32 + l4 * 8) * 2;
            a[mt] = *(const bf16x8*)(syB + row * 128 + (kb ^ ((row & 7) << 4)));
        }
        #pragma unroll
        for (int nt = 0; nt < 8; ++nt) {
            bf16x8 b = ldfrag(FR_W2 + ks * 8 + nt);
            #pragma unroll
            for (int mt = 0; mt < 3; ++mt) {
                f32x4& acc = (nt < 4) ? accS[mt][nt] : accR[mt][nt - 4];
                acc = __builtin_amdgcn_mfma_f32_16x16x32_bf16(a[mt], b, acc, 0, 0, 0);
            }
        }
    }
    __syncthreads();   // all reads of y1 done before overwrite with s1
    #pragma unroll
    for (int mt = 0; mt < 3; ++mt)
        #pragma unroll
        for (int j = 0; j < 4; ++j) {
            int row = mt * 16 + l4 * 4 + j;
            int sw  = (row & 7) << 4;
            #pragma unroll
            for (int nt = 0; nt < 4; ++nt) {
                int col = nt * 16 + l15;
                *(short*)(syB + row * 128 + ((col * 2) ^ sw)) =
                    (short)f2bf(fmaxf(accS[mt][nt][j], 0.f));
            }
        }
    __syncthreads();

    // ============ tconv1 ============
    #pragma unroll
    for (int dt = 0; dt < 3; ++dt) {
        #pragma unroll
        for (int ks = 0; ks < 2; ++ks) {
            bf16x8 a[3];
            #pragma unroll
            for (int mt = 0; mt < 3; ++mt) {
                int ts    = tA[mt] + dt - 1;
                bool ok   = (ts >= 0) && (ts < 12);
                int srow  = ok ? (rowA[mt] + dt - 1) : rowA[mt];
                int kb    = (ks * 32 + l4 * 8) * 2;
                bf16x8 av = *(const bf16x8*)(syB + srow * 128 + (kb ^ ((srow & 7) << 4)));
                a[mt] = ok ? av : (bf16x8)(short)0;
            }
            #pragma unroll
            for (int nt = 0; nt < 4; ++nt) {
                bf16x8 b = ldfrag(FR_TW1 + dt * 8 + ks * 4 + nt);
                #pragma unroll
                for (int mt = 0; mt < 3; ++mt)
                    accR[mt][nt] = __builtin_amdgcn_mfma_f32_16x16x32_bf16(a[mt], b, accR[mt][nt], 0, 0, 0);
            }
        }
    }
    __syncthreads();

    // ============ bias + relu + LN1 -> y2 into final buffer (16x768) ============
    {
        float bv[4], lgv[4], lbv[4];
        #pragma unroll
        for (int nt = 0; nt < 4; ++nt) {
            int col = nt * 16 + l15;
            bv[nt]  = rb1[col] + tb1[col];
            lgv[nt] = lg1[col];
            lbv[nt] = lb1[col];
        }
        #pragma unroll
        for (int mt = 0; mt < 3; ++mt)
            #pragma unroll
            for (int j = 0; j < 4; ++j) {
                float v[4], sm = 0.f, sq = 0.f;
                #pragma unroll
                for (int nt = 0; nt < 4; ++nt) {
                    v[nt] = fmaxf(accR[mt][nt][j] + bv[nt], 0.f);
                    sm += v[nt]; sq += v[nt] * v[nt];
                }
                #pragma unroll
                for (int m = 8; m; m >>= 1) {
                    sm += __shfl_xor(sm, m, 64);
                    sq += __shfl_xor(sq, m, 64);
                }
                float mu = sm * 0.015625f;
                float is = rsqrtf(sq * 0.015625f - mu * mu + 1e-5f);
                int row = mt * 16 + l4 * 4 + j;
                int p   = row / 12;
                int t   = row - p * 12;
                int gp  = wave * 4 + p;
                int sw  = (gp & 7) << 4;
                #pragma unroll
                for (int nt = 0; nt < 4; ++nt) {
                    int k = t * 64 + nt * 16 + l15;
                    *(short*)(LDS_FB + gp * 1536 + ((k * 2) ^ sw)) =
                        (short)f2bf((v[nt] - mu) * is * lgv[nt] + lbv[nt]);
                }
            }
    }
    __syncthreads();

    // ============ final: y2(16x768) @ FW(768x16), ks split across waves ============
    {
        f32x4 accF = (f32x4)0.f;
        #pragma unroll
        for (int q = 0; q < 6; ++q) {
            int ks = wave * 6 + q;
            int kb = (ks * 32 + l4 * 8) * 2;
            bf16x8 a = *(const bf16x8*)(LDS_FB + l15 * 1536 + (kb ^ ((l15 & 7) << 4)));
            bf16x8 b = ldfrag(FR_FW + ks);
            accF = __builtin_amdgcn_mfma_f32_16x16x32_bf16(a, b, accF, 0, 0, 0);
        }
        #pragma unroll
        for (int j = 0; j < 4; ++j)
            LDS_PB[wave * 256 + (l4 * 4 + j) * 16 + l15] = accF[j];
    }
    __syncthreads();
    {
        int tid = threadIdx.x;
        int gp = tid >> 4, po = tid & 15;
        if (po < 12) {
            float s = LDS_PB[gp * 16 + po] + LDS_PB[256 + gp * 16 + po]
                    + LDS_PB[512 + gp * 16 + po] + LDS_PB[768 + gp * 16 + po];
            out[(long)(blockIdx.x * 16 + gp) * 12 + po] = s + fb[po];
        }
    }
}

extern "C" void kernel_launch(void* const* d_in, const int* in_sizes, int n_in,
                              void* d_out, int out_size, void* d_ws, size_t ws_size,
                              hipStream_t stream)
{
    (void)in_sizes; (void)n_in; (void)out_size; (void)ws_size;
    const float* x   = (const float*)d_in[0];
    const float* th0 = (const float*)d_in[1];
    const float* tw0 = (const float*)d_in[2];
    const float* tb0 = (const float*)d_in[3];
    const float* rw0 = (const float*)d_in[4];
    const float* rb0 = (const float*)d_in[5];
    const float* lg0 = (const float*)d_in[6];
    const float* lb0 = (const float*)d_in[7];
    const float* th1 = (const float*)d_in[8];
    const float* tw1 = (const float*)d_in[9];
    const float* tb1 = (const float*)d_in[10];
    const float* rw1 = (const float*)d_in[11];
    const float* rb1 = (const float*)d_in[12];
    const float* lg1 = (const float*)d_in[13];
    const float* lb1 = (const float*)d_in[14];
    const float* fw  = (const float*)d_in[15];
    const float* fb  = (const float*)d_in[16];
    float* out = (float*)d_out;
    short* wsb = (short*)d_ws;

    prep<<<240, 256, 0, stream>>>(th0, tw0, rw0, th1, tw1, rw1, fw, wsb);
    mstgcn_mfma<<<1024, 256, 0, stream>>>(x, wsb, tb0, rb0, lg0, lb0,
                                          tb1, rb1, lg1, lb1, fb, out);
}

// Round 3
// 60.795 us; speedup vs baseline: 6.8859x; 1.7131x over previous
//
#include <hip/hip_runtime.h>

// MSTGCN head — fused bf16-MFMA implementation (round 3).
// cheb = [I,-I,I] (identity adjacency) => graph conv = per-(b,n) GEMM with
// te = theta0 - theta1 + theta2.
//
// Decomposition: 16384 (b,n) pairs. Wave = 4 pairs = 48 rows = 3 M-tiles of 16.
// Block = 4 waves = 16 pairs. Grid = 1024.
//   GEMM1 : X(48x128)      @ [te0|rw0T](128x128) -> s | r      (96 MFMA)
//   tconv0: 3 shifted s(48x64) @ TW0_dt(64x64)  += r           (72 MFMA)
//   GEMM2 : y1(48x64)      @ [te1|rw1T](64x128)                (48 MFMA)
//   tconv1: like tconv0                                        (72 MFMA)
//   final : y2(16x768)     @ FW(768x16)  (ks split 6/wave)     ( 6 MFMA)
//
// Round-3 fixes vs round-2 (which spilled: WRITE_SIZE 52 MB of scratch):
//  - no runtime-selected references into acc arrays (static nt loops only)
//  - __launch_bounds__(256,2): VGPR cap 256, no spill
//  - per-wave s/y LDS tile needs NO __syncthreads (wave-private); only the
//    cross-wave final buffer keeps barriers (2 total).

typedef __attribute__((ext_vector_type(8))) short bf16x8;
typedef __attribute__((ext_vector_type(4))) float f32x4;

#define FR_W1   0     // 32 frags: ks(4)*8 + nt(8)   K=128,N=128 [te0|rw0T]
#define FR_TW0  32    // 24 frags: dt*8 + ks(2)*4 + nt(4)
#define FR_W2   56    // 16 frags: ks(2)*8 + nt(8)   K=64,N=128 [te1|rw1T]
#define FR_TW1  72    // 24 frags
#define FR_FW   96    // 24 frags: ks(24), N=16 (cols 12..15 zero)
#define N_FRAGS 120

__device__ __forceinline__ unsigned short f2bf(float f) {
    unsigned u = __builtin_bit_cast(unsigned, f);
    return (unsigned short)((u + 0x7FFFu + ((u >> 16) & 1u)) >> 16);
}

__global__ void prep(const float* __restrict__ th0, const float* __restrict__ tw0,
                     const float* __restrict__ rw0, const float* __restrict__ th1,
                     const float* __restrict__ tw1, const float* __restrict__ rw1,
                     const float* __restrict__ fw,  short* __restrict__ wsb)
{
    int e = blockIdx.x * 256 + threadIdx.x;     // (frag, lane, i)
    if (e >= N_FRAGS * 512) return;
    int frag = e >> 9;
    int l    = (e >> 3) & 63;
    int i    = e & 7;
    int kif  = ((l >> 4) << 3) + i;             // k within 32-chunk
    int nif  = l & 15;
    float val = 0.f;
    if (frag < 32) {                                       // W1
        int ks = frag >> 3, nt = frag & 7;
        int k = ks * 32 + kif, n = nt * 16 + nif;
        if (n < 64) val = th0[k*64+n] - th0[8192 + k*64+n] + th0[16384 + k*64+n];
        else        val = rw0[(n - 64) * 128 + k];
    } else if (frag < 56) {                                // TW0
        int q = frag - 32; int dt = q >> 3, ks = (q >> 2) & 1, nt = q & 3;
        int c = ks * 32 + kif, o = nt * 16 + nif;
        val = tw0[o * 192 + c * 3 + dt];
    } else if (frag < 72) {                                // W2
        int q = frag - 56; int ks = q >> 3, nt = q & 7;
        int k = ks * 32 + kif, n = nt * 16 + nif;
        if (n < 64) val = th1[k*64+n] - th1[4096 + k*64+n] + th1[8192 + k*64+n];
        else        val = rw1[(n - 64) * 64 + k];
    } else if (frag < 96) {                                // TW1
        int q = frag - 72; int dt = q >> 3, ks = (q >> 2) & 1, nt = q & 3;
        int c = ks * 32 + kif, o = nt * 16 + nif;
        val = tw1[o * 192 + c * 3 + dt];
    } else {                                               // FW
        int ks = frag - 96; int k = ks * 32 + kif; int po = nif;
        val = (po < 12) ? fw[po * 768 + k] : 0.f;
    }
    wsb[e] = (short)f2bf(val);
}

// LDS layout:
//   [0..24575]     : 4 per-wave 48x64 bf16 s/y tiles (6 KB each, XOR-swizzled,
//                    WAVE-PRIVATE -> no barriers)
//   [24576..49151] : final buffer 16 pairs x 768 bf16 (swizzled, cross-wave)
//   [49152..53247] : 4x16x16 f32 partials
#define LDS_SY(w)  (LDS + (w) * 6144)
#define LDS_FB     (LDS + 24576)
#define LDS_PB     ((float*)(LDS + 49152))

__global__ __launch_bounds__(256, 2) void mstgcn_mfma(
    const float* __restrict__ x,   const short* __restrict__ wsb,
    const float* __restrict__ tb0, const float* __restrict__ rb0,
    const float* __restrict__ lg0, const float* __restrict__ lb0,
    const float* __restrict__ tb1, const float* __restrict__ rb1,
    const float* __restrict__ lg1, const float* __restrict__ lb1,
    const float* __restrict__ fb,  float* __restrict__ out)
{
    __shared__ __align__(16) char LDS[53248];

    const int lane = threadIdx.x & 63;
    const int wave = threadIdx.x >> 6;
    const int l15  = lane & 15;
    const int l4   = lane >> 4;
    const int pair0 = blockIdx.x * 16 + wave * 4;

    char* syB = LDS_SY(wave);

    auto ldfrag = [&](int f) -> bf16x8 {
        return *(const bf16x8*)(wsb + f * 512 + lane * 8);
    };

    // A-row decode (rows 0..47 within wave; row -> (pair, t))
    int rowA[3], tA[3];
    long gbase[3];
    #pragma unroll
    for (int mt = 0; mt < 3; ++mt) {
        int r = mt * 16 + l15;
        int p = r / 12;
        rowA[mt] = r;
        tA[mt]   = r - p * 12;
        gbase[mt] = ((long)(pair0 + p) * 12 + tA[mt]) * 128;
    }

    // ============ GEMM1: X @ [te0 | rw0T] ============
    f32x4 accS[3][4] = {}, accR[3][4] = {};
    #pragma unroll
    for (int ks = 0; ks < 4; ++ks) {
        bf16x8 a[3];
        #pragma unroll
        for (int mt = 0; mt < 3; ++mt) {
            const float* p = x + gbase[mt] + ks * 32 + l4 * 8;
            float v[8];
            *(float4*)(v)     = *(const float4*)(p);
            *(float4*)(v + 4) = *(const float4*)(p + 4);
            bf16x8 af;
            #pragma unroll
            for (int j = 0; j < 8; ++j) af[j] = (short)f2bf(v[j]);
            a[mt] = af;
        }
        #pragma unroll
        for (int nt = 0; nt < 4; ++nt) {
            bf16x8 b = ldfrag(FR_W1 + ks * 8 + nt);
            #pragma unroll
            for (int mt = 0; mt < 3; ++mt)
                accS[mt][nt] = __builtin_amdgcn_mfma_f32_16x16x32_bf16(a[mt], b, accS[mt][nt], 0, 0, 0);
        }
        #pragma unroll
        for (int nt = 0; nt < 4; ++nt) {
            bf16x8 b = ldfrag(FR_W1 + ks * 8 + 4 + nt);
            #pragma unroll
            for (int mt = 0; mt < 3; ++mt)
                accR[mt][nt] = __builtin_amdgcn_mfma_f32_16x16x32_bf16(a[mt], b, accR[mt][nt], 0, 0, 0);
        }
    }
    // epilogue: s = relu(accS) -> LDS (swizzled bf16); wave-private, no barrier
    #pragma unroll
    for (int mt = 0; mt < 3; ++mt)
        #pragma unroll
        for (int j = 0; j < 4; ++j) {
            int row = mt * 16 + l4 * 4 + j;
            int sw  = (row & 7) << 4;
            #pragma unroll
            for (int nt = 0; nt < 4; ++nt) {
                int col = nt * 16 + l15;
                *(short*)(syB + row * 128 + ((col * 2) ^ sw)) =
                    (short)f2bf(fmaxf(accS[mt][nt][j], 0.f));
            }
        }

    // ============ tconv0 (3 shifted GEMMs), C-init = accR ============
    #pragma unroll
    for (int dt = 0; dt < 3; ++dt) {
        #pragma unroll
        for (int ks = 0; ks < 2; ++ks) {
            bf16x8 a[3];
            #pragma unroll
            for (int mt = 0; mt < 3; ++mt) {
                int ts    = tA[mt] + dt - 1;
                bool ok   = (ts >= 0) && (ts < 12);
                int srow  = ok ? (rowA[mt] + dt - 1) : rowA[mt];
                int kb    = (ks * 32 + l4 * 8) * 2;
                bf16x8 av = *(const bf16x8*)(syB + srow * 128 + (kb ^ ((srow & 7) << 4)));
                a[mt] = ok ? av : (bf16x8)(short)0;
            }
            #pragma unroll
            for (int nt = 0; nt < 4; ++nt) {
                bf16x8 b = ldfrag(FR_TW0 + dt * 8 + ks * 4 + nt);
                #pragma unroll
                for (int mt = 0; mt < 3; ++mt)
                    accR[mt][nt] = __builtin_amdgcn_mfma_f32_16x16x32_bf16(a[mt], b, accR[mt][nt], 0, 0, 0);
            }
        }
    }

    // ============ bias + relu + LN0 -> y1 into LDS (wave-private) ============
    {
        float bv[4], lgv[4], lbv[4];
        #pragma unroll
        for (int nt = 0; nt < 4; ++nt) {
            int col = nt * 16 + l15;
            bv[nt]  = rb0[col] + tb0[col];
            lgv[nt] = lg0[col];
            lbv[nt] = lb0[col];
        }
        #pragma unroll
        for (int mt = 0; mt < 3; ++mt)
            #pragma unroll
            for (int j = 0; j < 4; ++j) {
                float v[4], sm = 0.f, sq = 0.f;
                #pragma unroll
                for (int nt = 0; nt < 4; ++nt) {
                    v[nt] = fmaxf(accR[mt][nt][j] + bv[nt], 0.f);
                    sm += v[nt]; sq += v[nt] * v[nt];
                }
                #pragma unroll
                for (int m = 8; m; m >>= 1) {
                    sm += __shfl_xor(sm, m, 64);
                    sq += __shfl_xor(sq, m, 64);
                }
                float mu = sm * 0.015625f;
                float is = rsqrtf(sq * 0.015625f - mu * mu + 1e-5f);
                int row = mt * 16 + l4 * 4 + j;
                int sw  = (row & 7) << 4;
                #pragma unroll
                for (int nt = 0; nt < 4; ++nt) {
                    int col = nt * 16 + l15;
                    *(short*)(syB + row * 128 + ((col * 2) ^ sw)) =
                        (short)f2bf((v[nt] - mu) * is * lgv[nt] + lbv[nt]);
                }
            }
    }

    // ============ GEMM2: y1 @ [te1 | rw1T]  (K=64) ============
    #pragma unroll
    for (int mt = 0; mt < 3; ++mt)
        #pragma unroll
        for (int nt = 0; nt < 4; ++nt) { accS[mt][nt] = (f32x4)0.f; accR[mt][nt] = (f32x4)0.f; }
    #pragma unroll
    for (int ks = 0; ks < 2; ++ks) {
        bf16x8 a[3];
        #pragma unroll
        for (int mt = 0; mt < 3; ++mt) {
            int row = rowA[mt];
            int kb  = (ks * 32 + l4 * 8) * 2;
            a[mt] = *(const bf16x8*)(syB + row * 128 + (kb ^ ((row & 7) << 4)));
        }
        #pragma unroll
        for (int nt = 0; nt < 4; ++nt) {
            bf16x8 b = ldfrag(FR_W2 + ks * 8 + nt);
            #pragma unroll
            for (int mt = 0; mt < 3; ++mt)
                accS[mt][nt] = __builtin_amdgcn_mfma_f32_16x16x32_bf16(a[mt], b, accS[mt][nt], 0, 0, 0);
        }
        #pragma unroll
        for (int nt = 0; nt < 4; ++nt) {
            bf16x8 b = ldfrag(FR_W2 + ks * 8 + 4 + nt);
            #pragma unroll
            for (int mt = 0; mt < 3; ++mt)
                accR[mt][nt] = __builtin_amdgcn_mfma_f32_16x16x32_bf16(a[mt], b, accR[mt][nt], 0, 0, 0);
        }
    }
    // s1 = relu(accS) overwrites y1 tile (same wave: lgkm ordering suffices)
    #pragma unroll
    for (int mt = 0; mt < 3; ++mt)
        #pragma unroll
        for (int j = 0; j < 4; ++j) {
            int row = mt * 16 + l4 * 4 + j;
            int sw  = (row & 7) << 4;
            #pragma unroll
            for (int nt = 0; nt < 4; ++nt) {
                int col = nt * 16 + l15;
                *(short*)(syB + row * 128 + ((col * 2) ^ sw)) =
                    (short)f2bf(fmaxf(accS[mt][nt][j], 0.f));
            }
        }

    // ============ tconv1 ============
    #pragma unroll
    for (int dt = 0; dt < 3; ++dt) {
        #pragma unroll
        for (int ks = 0; ks < 2; ++ks) {
            bf16x8 a[3];
            #pragma unroll
            for (int mt = 0; mt < 3; ++mt) {
                int ts    = tA[mt] + dt - 1;
                bool ok   = (ts >= 0) && (ts < 12);
                int srow  = ok ? (rowA[mt] + dt - 1) : rowA[mt];
                int kb    = (ks * 32 + l4 * 8) * 2;
                bf16x8 av = *(const bf16x8*)(syB + srow * 128 + (kb ^ ((srow & 7) << 4)));
                a[mt] = ok ? av : (bf16x8)(short)0;
            }
            #pragma unroll
            for (int nt = 0; nt < 4; ++nt) {
                bf16x8 b = ldfrag(FR_TW1 + dt * 8 + ks * 4 + nt);
                #pragma unroll
                for (int mt = 0; mt < 3; ++mt)
                    accR[mt][nt] = __builtin_amdgcn_mfma_f32_16x16x32_bf16(a[mt], b, accR[mt][nt], 0, 0, 0);
            }
        }
    }

    // ============ bias + relu + LN1 -> y2 into final buffer (16x768) ============
    {
        float bv[4], lgv[4], lbv[4];
        #pragma unroll
        for (int nt = 0; nt < 4; ++nt) {
            int col = nt * 16 + l15;
            bv[nt]  = rb1[col] + tb1[col];
            lgv[nt] = lg1[col];
            lbv[nt] = lb1[col];
        }
        #pragma unroll
        for (int mt = 0; mt < 3; ++mt)
            #pragma unroll
            for (int j = 0; j < 4; ++j) {
                float v[4], sm = 0.f, sq = 0.f;
                #pragma unroll
                for (int nt = 0; nt < 4; ++nt) {
                    v[nt] = fmaxf(accR[mt][nt][j] + bv[nt], 0.f);
                    sm += v[nt]; sq += v[nt] * v[nt];
                }
                #pragma unroll
                for (int m = 8; m; m >>= 1) {
                    sm += __shfl_xor(sm, m, 64);
                    sq += __shfl_xor(sq, m, 64);
                }
                float mu = sm * 0.015625f;
                float is = rsqrtf(sq * 0.015625f - mu * mu + 1e-5f);
                int row = mt * 16 + l4 * 4 + j;
                int p   = row / 12;
                int t   = row - p * 12;
                int gp  = wave * 4 + p;
                int sw  = (gp & 7) << 4;
                #pragma unroll
                for (int nt = 0; nt < 4; ++nt) {
                    int k = t * 64 + nt * 16 + l15;
                    *(short*)(LDS_FB + gp * 1536 + ((k * 2) ^ sw)) =
                        (short)f2bf((v[nt] - mu) * is * lgv[nt] + lbv[nt]);
                }
            }
    }
    __syncthreads();   // FB is cross-wave

    // ============ final: y2(16x768) @ FW(768x16), ks split across waves ============
    {
        f32x4 accF = (f32x4)0.f;
        #pragma unroll
        for (int q = 0; q < 6; ++q) {
            int ks = wave * 6 + q;
            int kb = (ks * 32 + l4 * 8) * 2;
            bf16x8 a = *(const bf16x8*)(LDS_FB + l15 * 1536 + (kb ^ ((l15 & 7) << 4)));
            bf16x8 b = ldfrag(FR_FW + ks);
            accF = __builtin_amdgcn_mfma_f32_16x16x32_bf16(a, b, accF, 0, 0, 0);
        }
        #pragma unroll
        for (int j = 0; j < 4; ++j)
            LDS_PB[wave * 256 + (l4 * 4 + j) * 16 + l15] = accF[j];
    }
    __syncthreads();
    {
        int tid = threadIdx.x;
        int gp = tid >> 4, po = tid & 15;
        if (po < 12) {
            float s = LDS_PB[gp * 16 + po] + LDS_PB[256 + gp * 16 + po]
                    + LDS_PB[512 + gp * 16 + po] + LDS_PB[768 + gp * 16 + po];
            out[(long)(blockIdx.x * 16 + gp) * 12 + po] = s + fb[po];
        }
    }
}

extern "C" void kernel_launch(void* const* d_in, const int* in_sizes, int n_in,
                              void* d_out, int out_size, void* d_ws, size_t ws_size,
                              hipStream_t stream)
{
    (void)in_sizes; (void)n_in; (void)out_size; (void)ws_size;
    const float* x   = (const float*)d_in[0];
    const float* th0 = (const float*)d_in[1];
    const float* tw0 = (const float*)d_in[2];
    const float* tb0 = (const float*)d_in[3];
    const float* rw0 = (const float*)d_in[4];
    const float* rb0 = (const float*)d_in[5];
    const float* lg0 = (const float*)d_in[6];
    const float* lb0 = (const float*)d_in[7];
    const float* th1 = (const float*)d_in[8];
    const float* tw1 = (const float*)d_in[9];
    const float* tb1 = (const float*)d_in[10];
    const float* rw1 = (const float*)d_in[11];
    const float* rb1 = (const float*)d_in[12];
    const float* lg1 = (const float*)d_in[13];
    const float* lb1 = (const float*)d_in[14];
    const float* fw  = (const float*)d_in[15];
    const float* fb  = (const float*)d_in[16];
    float* out = (float*)d_out;
    short* wsb = (short*)d_ws;

    prep<<<240, 256, 0, stream>>>(th0, tw0, rw0, th1, tw1, rw1, fw, wsb);
    mstgcn_mfma<<<1024, 256, 0, stream>>>(x, wsb, tb0, rb0, lg0, lb0,
                                          tb1, rb1, lg1, lb1, fb, out);
}